// Round 8
// baseline (172.630 us; speedup 1.0000x reference)
//
#include <hip/hip_runtime.h>

// NCC loss, fused single pass. Layout [n][1][d][h][w], n=2, d=160, h=192, w=192, f32.
// R13: 8-wave (512-thread) blocks -- the residency-limiter discrimination test.
//   Model (fits all R5-R12 counters exactly): per wave-step ~650 wave64 VALU ops
//   (1300 issue-cyc) + 20 ds_read_b128; measured VALUBusy 50% and dur 82us solve to
//   concurrency C ~= 2 blocks/CU (8 waves/CU), giving makespan = 1944 x 21.6us /
//   (256x2) = 82.0us == measured. Static limits (VGPR<=128 -> 4 waves/SIMD, LDS
//   37.4KB -> 4 blocks) allow 16 waves/CU; something non-static pins ~2 BLOCKS (or
//   ~8 waves) per CU. Every prior work/sync optimization (R6 -33% LDS reads, R9
//   counted-vmcnt, R11 barrier-free, R12 row pipeline) was flat because the wall is
//   total_steps x tau / resident_waves and resident waves never moved.
//   Test: double waves per block (8 waves, H-tile 32, grid 3x6x54 = 972 blocks).
//   If the limiter is per-BLOCK: 16 waves/CU resident -> VALU saturates -> ~45-50us.
//   If per-WAVE: flat 82us -> next round cuts total steps (CD) instead.
//   LDS 8 x 9216B = 73.8KB/block; 2 blocks = 147.6KB <= 160KB (gfx950 static LDS
//   >64KB is known-good: m201 8-phase GEMM uses 128KB). R12's neutral fast path
//   reverted (back to R11 body, ~96 VGPR) for 4-waves/SIMD headroom.
// R11 (kept): barrier-free wave-private structure. Wave w owns output rows
//   hbase+4w..+3, stages its own 8 input rows (4+4 halo) of BOTH arrays into a
//   private 2-buffer LDS region; per-lane array select via global-address offset
//   (legal: only the LDS dest is lane-linear, m104/m108). Distance-1 private
//   prefetch: top of step issues 5 DMAs for slice s+1; bottom waits
//   s_waitcnt vmcnt(0) lgkmcnt(0) (own ops only; lgkmcnt closes the WAR window).
//   NO s_barrier in the D-loop; one __syncthreads before the final reduction.
// R6 (kept): aligned layout col c <-> w = wbase-2+c, 2x aligned ds_read_b128 per
//   row/array; W-edge clamp-shift fixed by in-register permute (fixl/fixr).
// R5 (kept): all lanes always issue DMA with CLAMPED global addrs; tail mask
//   (r=4: lane<32) keeps lane 0 active. H-OOB rows skipped in compute, D-OOB
//   slices skipped wave-uniformly, ring in registers, NO occupancy clamp
//   (R3/R10: a min-waves arg spills the ring -> ~1GB scratch traffic).

namespace {
constexpr int Wd = 192, Hd = 192, Dd = 160;
constexpr int SH = 192;              // h stride (floats)
constexpr int SD = 192 * 192;        // d stride
constexpr long SN = (long)SD * Dd;   // n stride
constexpr int CD = 6;                // d outputs per chunk; T = CD+4 = 10
constexpr int NCHUNK = 27;           // ceil(160/6)
constexpr int TROW = 72;             // floats per row (18 16B-segs)
constexpr int ARRF = 8 * TROW;       // 576 floats: one array's 8-row block
constexpr int BUFF = 2 * ARRF;       // 1152 floats: one slice buffer (I+J)
constexpr int WREGF = 2 * BUFF;      // 2304 floats: one wave's region (2 buffers)
constexpr int NW = 8;                // waves per block (R13: was 4)
constexpr float INV_V = 1.0f / 125.0f;
constexpr float EPSf = 1e-5f;

__device__ __forceinline__ void wslide(const float h[8], float o[4]) {
  float s0 = h[0] + h[1] + h[2] + h[3] + h[4];
  float s1 = s0 - h[0] + h[5];
  float s2 = s1 - h[1] + h[6];
  float s3 = s2 - h[2] + h[7];
  o[0] = s0; o[1] = s1; o[2] = s2; o[3] = s3;
}

__device__ __forceinline__ void gl_lds16(const float* g, float* l) {
  __builtin_amdgcn_global_load_lds(
      (const __attribute__((address_space(1))) void*)g,
      (__attribute__((address_space(3))) void*)l, 16, 0, 0);
}
} // namespace

__global__ __launch_bounds__(512) void ncc_fused(const float* __restrict__ I,
                                                 const float* __restrict__ Jv,
                                                 float* __restrict__ out) {
  __shared__ float tile[NW * WREGF];  // 8 waves x 9216 B = 73,728 B
  __shared__ float red[NW];

  const int tid  = threadIdx.x;
  const int lane = tid & 63, wave = tid >> 6;
  const int tx   = lane & 15;       // w-run index (4 outputs each)
  const int tyw  = lane >> 4;       // output row within wave's 4-row strip
  const int wbase = blockIdx.x * 64;
  const int hbase = blockIdx.y * 32;          // 32-tall H tile (8 waves x 4 rows)
  const int n   = blockIdx.z / NCHUNK;
  const int d_lo = (blockIdx.z % NCHUNK) * CD;
  const int hw0 = hbase + 4 * wave - 2;   // region row r <-> global h = hw0 + r

  const float* Ib = I  + (long)n * SN;
  const float* Jb = Jv + (long)n * SN;
  const long  dJ  = (long)(Jb - Ib);      // per-lane array select as an offset

  // ---- wave-private staging descriptors: 288 16B-segs over 5 issues/lane ----
  // seg = r*64+lane; arr = seg>=144; rem = seg - arr*144; row = rem/18; c16 = rem%18
  // LDS float offset within buffer = seg*4 (lane-linear per issue: base + lane*16B)
  long goffL[5]; int lloc[5]; bool on[5];
  #pragma unroll
  for (int r = 0; r < 5; ++r) {
    const int seg = r * 64 + lane;
    on[r] = (r < 4) || (lane < 32);              // 288 = 4*64 + 32 (lane 0 active)
    const int arr = (seg >= 144) ? 1 : 0;
    const int rem = seg - arr * 144;
    const int row = rem / 18, c16 = rem % 18;
    const int hh = hw0 + row;
    const int hc = min(max(hh, 0), Hd - 1);      // CLAMP, never mask
    const int gw = wbase - 2 + c16 * 4;
    const int gc = min(max(gw, 0), Wd - 4);
    goffL[r] = (arr ? dJ : 0L) + (long)(hc * SH + gc);
    lloc[r]  = seg * 4;                          // float offset
  }
  float* wreg = &tile[wave * WREGF];

  // ---- prologue: stage slice d_lo-2 into buf0 (wave-private, no barrier) ----
  if (d_lo > 0) {
    const float* base = Ib + (long)(d_lo - 2) * SD;
    #pragma unroll
    for (int r = 0; r < 5; ++r) if (on[r]) gl_lds16(base + goffL[r], wreg + lloc[r]);
  }
  asm volatile("s_waitcnt vmcnt(0) lgkmcnt(0)" ::: "memory");

  // W-edge fixups (layout col c <-> w = wbase-2+c): clamp-shifted segs only touch
  // these 2 thread-columns; true values live in other slots of the same read.
  const bool fixl = (wbase == 0)   && (tx == 0);
  const bool fixr = (wbase == 128) && (tx == 15);

  float ring[5][5][4];  // [phase][channel:{I,J,II,JJ,IJ}][k]
  float acc = 0.0f;

  int bcur = 0;  // current-slice buffer (0/1)
  constexpr int T = CD + 4; // 10 steps; output d = d_lo + t - 4 for t>=4
  for (int t0 = 0; t0 < T; t0 += 5) {
    #pragma unroll
    for (int p = 0; p < 5; ++p) {             // phase = t % 5 (compile-time)
      const int t = t0 + p;
      const int s = d_lo - 2 + t;             // slice in buf[bcur]

      // ---- private prefetch: slice s+1 -> buf[bcur^1], consumed next step ----
      const bool issue = ((t + 1) < T) && ((s + 1) >= 0) && ((s + 1) < Dd);
      if (issue) {
        const float* base = Ib + (long)(s + 1) * SD;
        float* dst = wreg + (bcur ^ 1) * BUFF;
        #pragma unroll
        for (int r = 0; r < 5; ++r) if (on[r]) gl_lds16(base + goffL[r], dst + lloc[r]);
      }

      // ---- H-window accumulate from private buffer ----
      float hsI[8], hsJ[8], hsII[8], hsJJ[8], hsIJ[8];
      #pragma unroll
      for (int c = 0; c < 8; ++c) {
        hsI[c] = 0.f; hsJ[c] = 0.f; hsII[c] = 0.f; hsJJ[c] = 0.f; hsIJ[c] = 0.f;
      }
      if (s >= 0 && s < Dd) {
        const float* bufc = wreg + bcur * BUFF;
        #pragma unroll
        for (int dh = 0; dh < 5; ++dh) {
          const int rrow = tyw + dh;           // region rows tyw..tyw+4 (of 8)
          const int hh = hw0 + rrow;
          if (hh >= 0 && hh < Hd) {            // skip clamped-duplicate halo rows
            const float* pa = bufc + rrow * TROW + 4 * tx;  // cols 4tx..4tx+7, 16B-aligned
            const float* pb = pa + ARRF;       // J block
            float a[8], b[8];
            ((float4*)a)[0] = ((const float4*)pa)[0];
            ((float4*)a)[1] = ((const float4*)pa)[1];
            ((float4*)b)[0] = ((const float4*)pb)[0];
            ((float4*)b)[1] = ((const float4*)pb)[1];
            if (fixl) { a[2]=a[0]; a[3]=a[1]; a[0]=0.f; a[1]=0.f;
                        b[2]=b[0]; b[3]=b[1]; b[0]=0.f; b[1]=0.f; }
            if (fixr) { a[4]=a[6]; a[5]=a[7]; a[6]=0.f; a[7]=0.f;
                        b[4]=b[6]; b[5]=b[7]; b[6]=0.f; b[7]=0.f; }
            #pragma unroll
            for (int c = 0; c < 8; ++c) {
              const float x = a[c], y = b[c];  // cols w0-2..w0+5
              hsI[c]  += x;
              hsJ[c]  += y;
              hsII[c] = fmaf(x, x, hsII[c]);
              hsJJ[c] = fmaf(y, y, hsJJ[c]);
              hsIJ[c] = fmaf(x, y, hsIJ[c]);
            }
          }
        }
      }

      // ---- W-window sliding sums -> ring ----
      wslide(hsI,  ring[p][0]);
      wslide(hsJ,  ring[p][1]);
      wslide(hsII, ring[p][2]);
      wslide(hsJJ, ring[p][3]);
      wslide(hsIJ, ring[p][4]);

      // ---- D-window + cc ----
      const int d = d_lo + t - 4;
      if (t >= 4 && d < Dd) {
        #pragma unroll
        for (int k = 0; k < 4; ++k) {
          float SI = 0.f, SJ = 0.f, SII = 0.f, SJJ = 0.f, SIJ = 0.f;
          #pragma unroll
          for (int q = 0; q < 5; ++q) {
            SI  += ring[q][0][k];
            SJ  += ring[q][1][k];
            SII += ring[q][2][k];
            SJJ += ring[q][3][k];
            SIJ += ring[q][4][k];
          }
          const float cross = SIJ - SI * SJ * INV_V;
          const float vI    = SII - SI * SI * INV_V;
          const float vJ    = SJJ - SJ * SJ * INV_V;
          acc += cross * cross / (vI * vJ + EPSf);
        }
      }

      // ---- wave-private drain: own prefetch landed, own ds_reads retired ----
      asm volatile("s_waitcnt vmcnt(0) lgkmcnt(0)" ::: "memory");
      bcur ^= 1;
    }
  }

  // ---- block reduction -> single atomic per block (only barrier in kernel) ----
  #pragma unroll
  for (int off = 32; off > 0; off >>= 1) acc += __shfl_xor(acc, off, 64);
  if (lane == 0) red[wave] = acc;
  __syncthreads();
  if (tid == 0) {
    float total = 0.f;
    #pragma unroll
    for (int w = 0; w < NW; ++w) total += red[w];
    atomicAdd(out, total * (-1.0f / 11796480.0f)); // -mean over 2*160*192*192
  }
}

extern "C" void kernel_launch(void* const* d_in, const int* in_sizes, int n_in,
                              void* d_out, int out_size, void* d_ws, size_t ws_size,
                              hipStream_t stream) {
  const float* I = (const float*)d_in[0];
  const float* J = (const float*)d_in[1];
  float* out = (float*)d_out;
  hipMemsetAsync(out, 0, sizeof(float), stream);
  dim3 grid(3, 6, 2 * NCHUNK); // W tiles * H tiles(32-tall) * (n x 27 d-chunks of 6)
  ncc_fused<<<grid, 512, 0, stream>>>(I, J, out);
}

// Round 9
// 157.026 us; speedup vs baseline: 1.0994x; 1.0994x over previous
//
#include <hip/hip_runtime.h>

// NCC loss, fused single pass. Layout [n][1][d][h][w], n=2, d=160, h=192, w=192, f32.
// R14: cut TOTAL wave-steps via CD=6 -> 16 (warm-up amortization).
//   Evidence: R5-R13 pin dur at 81-90us under -33% LDS reads (R6), counted-vmcnt
//   DMA pipeline (R9), zero barriers (R11), row software-pipeline (R12), 8-wave
//   blocks with 16-wave/CU static residency (R13). Occupancy counter ~19-26%
//   (~6-8 waves/CU) in ALL of them; both VALU and LDS pipes ~50%. Model
//   wall = total_wave_steps x tau / resident_waves fits every round. Residency
//   won't move (2 direct tests) -> reduce total work instead. Each D-chunk of CD
//   outputs processes CD+4 slices; slice-processings = 160*(1+4/CD):
//   CD=6 -> 267, CD=16 -> 200 (-25%), 160 = 10*16 exact, T = 20 = 4x5 phases.
//   Grid 3x12x20 = 720 blocks (~2.8/CU at the observed C~2: ~5% tail imbalance,
//   net ~-20%). Per-step code path unchanged; block config reverted to the best
//   variant (R11: 4 waves / 256 threads / 36.9KB LDS).
// R11 (kept): barrier-free wave-private structure. Wave w owns output rows
//   hbase+4w..+3, stages its own 8 input rows (4+4 halo) of BOTH arrays into a
//   private 2-buffer LDS region; per-lane array select via global-address offset
//   (legal: only the LDS dest is lane-linear, m104/m108). Distance-1 private
//   prefetch: top of step issues 5 DMAs for slice s+1; bottom waits
//   s_waitcnt vmcnt(0) lgkmcnt(0) (own ops only; lgkmcnt closes the WAR window).
//   NO s_barrier in the D-loop; one __syncthreads before the final reduction.
// R6 (kept): aligned layout col c <-> w = wbase-2+c, 2x aligned ds_read_b128 per
//   row/array; W-edge clamp-shift fixed by in-register permute (fixl/fixr).
// R5 (kept): all lanes always issue DMA with CLAMPED global addrs; tail mask
//   (r=4: lane<32) keeps lane 0 active. H-OOB rows skipped in compute, D-OOB
//   slices skipped wave-uniformly, ring in registers, NO occupancy clamp
//   (R3/R10: a min-waves arg spills the ring -> ~1GB scratch traffic).

namespace {
constexpr int Wd = 192, Hd = 192, Dd = 160;
constexpr int SH = 192;              // h stride (floats)
constexpr int SD = 192 * 192;        // d stride
constexpr long SN = (long)SD * Dd;   // n stride
constexpr int CD = 16;               // d outputs per chunk; T = CD+4 = 20 (R14: was 6)
constexpr int NCHUNK = 10;           // 160/16 exact
constexpr int TROW = 72;             // floats per row (18 16B-segs)
constexpr int ARRF = 8 * TROW;       // 576 floats: one array's 8-row block
constexpr int BUFF = 2 * ARRF;       // 1152 floats: one slice buffer (I+J)
constexpr int WREGF = 2 * BUFF;      // 2304 floats: one wave's region (2 buffers)
constexpr int NW = 4;                // waves per block (reverted to R11 config)
constexpr float INV_V = 1.0f / 125.0f;
constexpr float EPSf = 1e-5f;

__device__ __forceinline__ void wslide(const float h[8], float o[4]) {
  float s0 = h[0] + h[1] + h[2] + h[3] + h[4];
  float s1 = s0 - h[0] + h[5];
  float s2 = s1 - h[1] + h[6];
  float s3 = s2 - h[2] + h[7];
  o[0] = s0; o[1] = s1; o[2] = s2; o[3] = s3;
}

__device__ __forceinline__ void gl_lds16(const float* g, float* l) {
  __builtin_amdgcn_global_load_lds(
      (const __attribute__((address_space(1))) void*)g,
      (__attribute__((address_space(3))) void*)l, 16, 0, 0);
}
} // namespace

__global__ __launch_bounds__(256) void ncc_fused(const float* __restrict__ I,
                                                 const float* __restrict__ Jv,
                                                 float* __restrict__ out) {
  __shared__ float tile[NW * WREGF];  // 4 waves x 9216 B = 36,864 B
  __shared__ float red[NW];

  const int tid  = threadIdx.x;
  const int lane = tid & 63, wave = tid >> 6;
  const int tx   = lane & 15;       // w-run index (4 outputs each)
  const int tyw  = lane >> 4;       // output row within wave's 4-row strip
  const int wbase = blockIdx.x * 64;
  const int hbase = blockIdx.y * 16;          // 16-tall H tile (4 waves x 4 rows)
  const int n   = blockIdx.z / NCHUNK;
  const int d_lo = (blockIdx.z % NCHUNK) * CD;
  const int hw0 = hbase + 4 * wave - 2;   // region row r <-> global h = hw0 + r

  const float* Ib = I  + (long)n * SN;
  const float* Jb = Jv + (long)n * SN;
  const long  dJ  = (long)(Jb - Ib);      // per-lane array select as an offset

  // ---- wave-private staging descriptors: 288 16B-segs over 5 issues/lane ----
  // seg = r*64+lane; arr = seg>=144; rem = seg - arr*144; row = rem/18; c16 = rem%18
  // LDS float offset within buffer = seg*4 (lane-linear per issue: base + lane*16B)
  long goffL[5]; int lloc[5]; bool on[5];
  #pragma unroll
  for (int r = 0; r < 5; ++r) {
    const int seg = r * 64 + lane;
    on[r] = (r < 4) || (lane < 32);              // 288 = 4*64 + 32 (lane 0 active)
    const int arr = (seg >= 144) ? 1 : 0;
    const int rem = seg - arr * 144;
    const int row = rem / 18, c16 = rem % 18;
    const int hh = hw0 + row;
    const int hc = min(max(hh, 0), Hd - 1);      // CLAMP, never mask
    const int gw = wbase - 2 + c16 * 4;
    const int gc = min(max(gw, 0), Wd - 4);
    goffL[r] = (arr ? dJ : 0L) + (long)(hc * SH + gc);
    lloc[r]  = seg * 4;                          // float offset
  }
  float* wreg = &tile[wave * WREGF];

  // ---- prologue: stage slice d_lo-2 into buf0 (wave-private, no barrier) ----
  if (d_lo > 0) {
    const float* base = Ib + (long)(d_lo - 2) * SD;
    #pragma unroll
    for (int r = 0; r < 5; ++r) if (on[r]) gl_lds16(base + goffL[r], wreg + lloc[r]);
  }
  asm volatile("s_waitcnt vmcnt(0) lgkmcnt(0)" ::: "memory");

  // W-edge fixups (layout col c <-> w = wbase-2+c): clamp-shifted segs only touch
  // these 2 thread-columns; true values live in other slots of the same read.
  const bool fixl = (wbase == 0)   && (tx == 0);
  const bool fixr = (wbase == 128) && (tx == 15);

  float ring[5][5][4];  // [phase][channel:{I,J,II,JJ,IJ}][k]
  float acc = 0.0f;

  int bcur = 0;  // current-slice buffer (0/1)
  constexpr int T = CD + 4; // 20 steps; output d = d_lo + t - 4 for t>=4
  for (int t0 = 0; t0 < T; t0 += 5) {
    #pragma unroll
    for (int p = 0; p < 5; ++p) {             // phase = t % 5 (compile-time)
      const int t = t0 + p;
      const int s = d_lo - 2 + t;             // slice in buf[bcur]

      // ---- private prefetch: slice s+1 -> buf[bcur^1], consumed next step ----
      const bool issue = ((t + 1) < T) && ((s + 1) >= 0) && ((s + 1) < Dd);
      if (issue) {
        const float* base = Ib + (long)(s + 1) * SD;
        float* dst = wreg + (bcur ^ 1) * BUFF;
        #pragma unroll
        for (int r = 0; r < 5; ++r) if (on[r]) gl_lds16(base + goffL[r], dst + lloc[r]);
      }

      // ---- H-window accumulate from private buffer ----
      float hsI[8], hsJ[8], hsII[8], hsJJ[8], hsIJ[8];
      #pragma unroll
      for (int c = 0; c < 8; ++c) {
        hsI[c] = 0.f; hsJ[c] = 0.f; hsII[c] = 0.f; hsJJ[c] = 0.f; hsIJ[c] = 0.f;
      }
      if (s >= 0 && s < Dd) {
        const float* bufc = wreg + bcur * BUFF;
        #pragma unroll
        for (int dh = 0; dh < 5; ++dh) {
          const int rrow = tyw + dh;           // region rows tyw..tyw+4 (of 8)
          const int hh = hw0 + rrow;
          if (hh >= 0 && hh < Hd) {            // skip clamped-duplicate halo rows
            const float* pa = bufc + rrow * TROW + 4 * tx;  // cols 4tx..4tx+7, 16B-aligned
            const float* pb = pa + ARRF;       // J block
            float a[8], b[8];
            ((float4*)a)[0] = ((const float4*)pa)[0];
            ((float4*)a)[1] = ((const float4*)pa)[1];
            ((float4*)b)[0] = ((const float4*)pb)[0];
            ((float4*)b)[1] = ((const float4*)pb)[1];
            if (fixl) { a[2]=a[0]; a[3]=a[1]; a[0]=0.f; a[1]=0.f;
                        b[2]=b[0]; b[3]=b[1]; b[0]=0.f; b[1]=0.f; }
            if (fixr) { a[4]=a[6]; a[5]=a[7]; a[6]=0.f; a[7]=0.f;
                        b[4]=b[6]; b[5]=b[7]; b[6]=0.f; b[7]=0.f; }
            #pragma unroll
            for (int c = 0; c < 8; ++c) {
              const float x = a[c], y = b[c];  // cols w0-2..w0+5
              hsI[c]  += x;
              hsJ[c]  += y;
              hsII[c] = fmaf(x, x, hsII[c]);
              hsJJ[c] = fmaf(y, y, hsJJ[c]);
              hsIJ[c] = fmaf(x, y, hsIJ[c]);
            }
          }
        }
      }

      // ---- W-window sliding sums -> ring ----
      wslide(hsI,  ring[p][0]);
      wslide(hsJ,  ring[p][1]);
      wslide(hsII, ring[p][2]);
      wslide(hsJJ, ring[p][3]);
      wslide(hsIJ, ring[p][4]);

      // ---- D-window + cc ----
      const int d = d_lo + t - 4;
      if (t >= 4 && d < Dd) {
        #pragma unroll
        for (int k = 0; k < 4; ++k) {
          float SI = 0.f, SJ = 0.f, SII = 0.f, SJJ = 0.f, SIJ = 0.f;
          #pragma unroll
          for (int q = 0; q < 5; ++q) {
            SI  += ring[q][0][k];
            SJ  += ring[q][1][k];
            SII += ring[q][2][k];
            SJJ += ring[q][3][k];
            SIJ += ring[q][4][k];
          }
          const float cross = SIJ - SI * SJ * INV_V;
          const float vI    = SII - SI * SI * INV_V;
          const float vJ    = SJJ - SJ * SJ * INV_V;
          acc += cross * cross / (vI * vJ + EPSf);
        }
      }

      // ---- wave-private drain: own prefetch landed, own ds_reads retired ----
      asm volatile("s_waitcnt vmcnt(0) lgkmcnt(0)" ::: "memory");
      bcur ^= 1;
    }
  }

  // ---- block reduction -> single atomic per block (only barrier in kernel) ----
  #pragma unroll
  for (int off = 32; off > 0; off >>= 1) acc += __shfl_xor(acc, off, 64);
  if (lane == 0) red[wave] = acc;
  __syncthreads();
  if (tid == 0) {
    float total = 0.f;
    #pragma unroll
    for (int w = 0; w < NW; ++w) total += red[w];
    atomicAdd(out, total * (-1.0f / 11796480.0f)); // -mean over 2*160*192*192
  }
}

extern "C" void kernel_launch(void* const* d_in, const int* in_sizes, int n_in,
                              void* d_out, int out_size, void* d_ws, size_t ws_size,
                              hipStream_t stream) {
  const float* I = (const float*)d_in[0];
  const float* J = (const float*)d_in[1];
  float* out = (float*)d_out;
  hipMemsetAsync(out, 0, sizeof(float), stream);
  dim3 grid(3, 12, 2 * NCHUNK); // W tiles * H tiles(16) * (n x 10 d-chunks of 16)
  ncc_fused<<<grid, 256, 0, stream>>>(I, J, out);
}